// Round 1
// baseline (378.682 us; speedup 1.0000x reference)
//
#include <hip/hip_runtime.h>
#include <math.h>

typedef unsigned int u32;

#define B_G 16
#define S_MAX 512
#define NH 8
#define DH 32
#define HD 256
#define FFD 1024
#define ADJW (S_MAX / 32)   // 16 u32 words per adjacency row

// ---------- helpers: manual bf16 (RNE) to avoid class-type shared arrays ----------
__device__ __forceinline__ unsigned short f2bf(float f) {
  u32 u = __float_as_uint(f);
  u += 0x7fffu + ((u >> 16) & 1u);
  return (unsigned short)(u >> 16);
}
__device__ __forceinline__ float bf2f(unsigned short s) {
  return __uint_as_float(((u32)s) << 16);
}

// ---------- graph offsets via binary search (batch is sorted) ----------
__global__ void k_offsets(const int* __restrict__ batch, int N, int* __restrict__ offs) {
  int g = threadIdx.x;
  if (g > B_G) return;
  if (g == B_G) { offs[B_G] = N; return; }
  int lo = 0, hi = N;
  while (lo < hi) { int mid = (lo + hi) >> 1; if (batch[mid] < g) lo = mid + 1; else hi = mid; }
  offs[g] = lo;
}

// ---------- scatter nodes into dense [B,S,H] (x pre-zeroed) + rowmap ----------
__global__ void k_scatter(const float* __restrict__ h, const int* __restrict__ batch,
                          const int* __restrict__ offs, float* __restrict__ x,
                          int* __restrict__ rowmap) {
  int i = blockIdx.x;          // node
  int c = threadIdx.x;         // 64 threads, float4 each
  int b = batch[i];
  int row = b * S_MAX + (i - offs[b]);
  if (c == 0) rowmap[i] = row;
  const float4* src = (const float4*)(h + (size_t)i * HD);
  float4* dst = (float4*)(x + (size_t)row * HD);
  dst[c] = src[c];
}

// ---------- adjacency bitmask: bit set => edge => -inf in mask ----------
__global__ void k_adj(const int* __restrict__ ei, int E, const int* __restrict__ batch,
                      const int* __restrict__ offs, u32* __restrict__ adj) {
  int e = blockIdx.x * 256 + threadIdx.x;
  if (e >= E) return;
  int s = ei[e], d = ei[E + e];
  int b = batch[s];
  int o = offs[b];
  int ps = s - o, pd = d - o;
  atomicOr(&adj[(b * S_MAX + ps) * ADJW + (pd >> 5)], 1u << (pd & 31));
}

// ---------- fp32 tiled GEMM: C[m,n] = sum_k A[rowmap?[m], k] * W[n,k] + bias[n] ----------
// BM=BN=64, BK=16, 256 threads, 4x4 per thread. M % 64 == 0, N % 64 == 0, K % 16 == 0.
template<bool RELU>
__global__ __launch_bounds__(256) void k_gemm(const float* __restrict__ A,
    const float* __restrict__ W, const float* __restrict__ bias,
    float* __restrict__ C, int N, int K, const int* __restrict__ rowmap) {
  __shared__ float As[16][68];
  __shared__ float Ws[16][68];
  int tid = threadIdx.x;
  int tx = tid & 15, ty = tid >> 4;
  int rl = tid >> 2, kq = tid & 3;
  int am = blockIdx.x * 64 + rl;
  int ar = rowmap ? rowmap[am] : am;
  const float* Arow = A + (size_t)ar * K + kq * 4;
  const float* Wrow = W + (size_t)(blockIdx.y * 64 + rl) * K + kq * 4;
  float acc[4][4] = {};
  for (int k0 = 0; k0 < K; k0 += 16) {
    float4 av = *(const float4*)(Arow + k0);
    float4 wv = *(const float4*)(Wrow + k0);
    __syncthreads();
    As[kq * 4 + 0][rl] = av.x; As[kq * 4 + 1][rl] = av.y;
    As[kq * 4 + 2][rl] = av.z; As[kq * 4 + 3][rl] = av.w;
    Ws[kq * 4 + 0][rl] = wv.x; Ws[kq * 4 + 1][rl] = wv.y;
    Ws[kq * 4 + 2][rl] = wv.z; Ws[kq * 4 + 3][rl] = wv.w;
    __syncthreads();
    #pragma unroll
    for (int kk = 0; kk < 16; kk++) {
      const float4 a = *(const float4*)&As[kk][ty * 4];
      const float4 bw = *(const float4*)&Ws[kk][tx * 4];
      float a4[4] = {a.x, a.y, a.z, a.w};
      float b4[4] = {bw.x, bw.y, bw.z, bw.w};
      #pragma unroll
      for (int i = 0; i < 4; i++)
        #pragma unroll
        for (int j = 0; j < 4; j++)
          acc[i][j] += a4[i] * b4[j];
    }
  }
  int nbase = blockIdx.y * 64 + tx * 4;
  size_t mbase = (size_t)blockIdx.x * 64 + ty * 4;
  const float4 bv = *(const float4*)&bias[nbase];
  float bb[4] = {bv.x, bv.y, bv.z, bv.w};
  #pragma unroll
  for (int i = 0; i < 4; i++) {
    float4 o;
    float t0 = acc[i][0] + bb[0], t1 = acc[i][1] + bb[1];
    float t2 = acc[i][2] + bb[2], t3 = acc[i][3] + bb[3];
    if (RELU) { t0 = fmaxf(t0, 0.f); t1 = fmaxf(t1, 0.f); t2 = fmaxf(t2, 0.f); t3 = fmaxf(t3, 0.f); }
    o.x = t0; o.y = t1; o.z = t2; o.w = t3;
    *(float4*)&C[(mbase + i) * N + nbase] = o;
  }
}

// ---------- fused masked attention: one block per (b, head, row-quarter) ----------
// K staged to LDS as bf16, transposed [c][t] with XOR swizzle (t^c) for bank-conflict-free
// reads in both phases. V == K (faithful to reference). 4 rows per wave per pass.
__global__ __launch_bounds__(256) void k_attn(
    const float* __restrict__ Q, const float* __restrict__ K,
    const u32* __restrict__ adj, const int* __restrict__ offs,
    float* __restrict__ attO) {
  int bid = blockIdx.x;            // 512 blocks: b(4b) | h(3b) | qtr(2b)
  int qtr = bid & 3;
  int h = (bid >> 2) & (NH - 1);
  int b = bid >> 5;
  int len = offs[b + 1] - offs[b];
  int rstart = qtr * 128;
  if (rstart >= len) return;
  int rend = rstart + 128; if (rend > len) rend = len;

  __shared__ __align__(16) unsigned short Ksh[32 * 512];     // [c][t^c], bf16, 32KB
  __shared__ __align__(16) unsigned short psh[4][512][4];    // per-wave p, 4 rows, 16KB

  int tid = threadIdx.x;
  {
    int c = tid & 31, t0 = tid >> 5;
    const float* Kg = K + (size_t)(b * S_MAX) * HD + h * DH + c;
    for (int t = t0; t < S_MAX; t += 8)
      Ksh[c * 512 + (t ^ c)] = f2bf(Kg[(size_t)t * HD]);
  }
  __syncthreads();

  int w = tid >> 6, lane = tid & 63;
  const float scale = 0.17677669529663687f;  // 1/sqrt(32)
  const float NEG_INF = -__builtin_inff();

  for (int r0 = rstart + w * 4; r0 < rend; r0 += 16) {
    // q for rows r0..r0+3 (r0 % 4 == 0 so r0+3 <= 511; rows >= rend computed but not stored)
    float qv[4];
    #pragma unroll
    for (int rr = 0; rr < 4; rr++)
      qv[rr] = Q[(size_t)(b * S_MAX + r0 + rr) * HD + h * DH + (lane & 31)];

    // logits: lane owns t = lane + 64*i
    float acc[4][8];
    #pragma unroll
    for (int rr = 0; rr < 4; rr++)
      #pragma unroll
      for (int i = 0; i < 8; i++) acc[rr][i] = 0.f;

    #pragma unroll 4
    for (int c = 0; c < 32; c++) {
      float qc0 = __shfl(qv[0], c, 64);
      float qc1 = __shfl(qv[1], c, 64);
      float qc2 = __shfl(qv[2], c, 64);
      float qc3 = __shfl(qv[3], c, 64);
      const unsigned short* Kc = &Ksh[c * 512];
      #pragma unroll
      for (int i = 0; i < 8; i++) {
        float kf = bf2f(Kc[(lane + 64 * i) ^ c]);
        acc[0][i] += qc0 * kf;
        acc[1][i] += qc1 * kf;
        acc[2][i] += qc2 * kf;
        acc[3][i] += qc3 * kf;
      }
    }

    // mask (edges get -inf) + softmax per row
    #pragma unroll
    for (int rr = 0; rr < 4; rr++) {
      const u32* aw = adj + ((size_t)(b * S_MAX + r0 + rr) * ADJW) + (lane >> 5);
      float m = NEG_INF;
      #pragma unroll
      for (int i = 0; i < 8; i++) {
        u32 word = aw[2 * i];
        float lg = ((word >> (lane & 31)) & 1u) ? NEG_INF : acc[rr][i] * scale;
        acc[rr][i] = lg;
        m = fmaxf(m, lg);
      }
      #pragma unroll
      for (int o = 1; o < 64; o <<= 1) m = fmaxf(m, __shfl_xor(m, o, 64));
      float s = 0.f;
      #pragma unroll
      for (int i = 0; i < 8; i++) { float p = __expf(acc[rr][i] - m); acc[rr][i] = p; s += p; }
      #pragma unroll
      for (int o = 1; o < 64; o <<= 1) s += __shfl_xor(s, o, 64);
      float inv = 1.f / s;
      #pragma unroll
      for (int i = 0; i < 8; i++) acc[rr][i] *= inv;
    }

    // stage p (bf16, 4 rows packed per t) for the PV phase
    #pragma unroll
    for (int i = 0; i < 8; i++) {
      int t = lane + 64 * i;
      psh[w][t][0] = f2bf(acc[0][i]);
      psh[w][t][1] = f2bf(acc[1][i]);
      psh[w][t][2] = f2bf(acc[2][i]);
      psh[w][t][3] = f2bf(acc[3][i]);
    }
    __threadfence_block();  // same-wave LDS write->read ordering

    // PV: lane owns (c = lane&31, half = lane>>5); V == K
    int c = lane & 31, hh = lane >> 5;
    float o0 = 0.f, o1 = 0.f, o2 = 0.f, o3 = 0.f;
    const unsigned short* Kc = &Ksh[c * 512];
    #pragma unroll 4
    for (int tt = 0; tt < 256; tt++) {
      int t = hh * 256 + tt;
      float kf = bf2f(Kc[t ^ c]);
      uint2 pv = *(const uint2*)&psh[w][t][0];
      o0 += kf * __uint_as_float(pv.x << 16);
      o1 += kf * __uint_as_float(pv.x & 0xffff0000u);
      o2 += kf * __uint_as_float(pv.y << 16);
      o3 += kf * __uint_as_float(pv.y & 0xffff0000u);
    }
    o0 += __shfl_down(o0, 32, 64);
    o1 += __shfl_down(o1, 32, 64);
    o2 += __shfl_down(o2, 32, 64);
    o3 += __shfl_down(o3, 32, 64);
    if (lane < 32) {
      float ov[4] = {o0, o1, o2, o3};
      #pragma unroll
      for (int rr = 0; rr < 4; rr++)
        if (r0 + rr < rend)
          attO[(size_t)(b * S_MAX + r0 + rr) * HD + h * DH + c] = ov[rr];
    }
  }
}

// ---------- LayerNorm(a + res) * g + be, one block (256 thr) per row ----------
__global__ __launch_bounds__(256) void k_ln(const float* __restrict__ a,
    const float* __restrict__ res, const float* __restrict__ g,
    const float* __restrict__ be, float* __restrict__ out) {
  int n = blockIdx.x, c = threadIdx.x;
  float v = a[(size_t)n * HD + c] + res[(size_t)n * HD + c];
  float s = v, q = v * v;
  #pragma unroll
  for (int o = 1; o < 64; o <<= 1) { s += __shfl_xor(s, o, 64); q += __shfl_xor(q, o, 64); }
  __shared__ float red[8];
  int w = c >> 6, lane = c & 63;
  if (lane == 0) { red[w] = s; red[4 + w] = q; }
  __syncthreads();
  s = red[0] + red[1] + red[2] + red[3];
  q = red[4] + red[5] + red[6] + red[7];
  float mu = s * (1.f / HD);
  float var = q * (1.f / HD) - mu * mu;
  float inv = rsqrtf(var + 1e-5f);
  out[(size_t)n * HD + c] = (v - mu) * inv * g[c] + be[c];
}

extern "C" void kernel_launch(void* const* d_in, const int* in_sizes, int n_in,
                              void* d_out, int out_size, void* d_ws, size_t ws_size,
                              hipStream_t stream) {
  const float* h   = (const float*)d_in[0];
  const float* Wq  = (const float*)d_in[1];
  const float* bq  = (const float*)d_in[2];
  const float* Wk  = (const float*)d_in[3];
  const float* bk  = (const float*)d_in[4];
  // d_in[5], d_in[6] (Wv, bv) intentionally unused: reference V uses the K projection
  const float* Wo  = (const float*)d_in[7];
  const float* bo  = (const float*)d_in[8];
  const float* W1  = (const float*)d_in[9];
  const float* b1  = (const float*)d_in[10];
  const float* W2  = (const float*)d_in[11];
  const float* b2  = (const float*)d_in[12];
  const float* g1  = (const float*)d_in[13];
  const float* be1 = (const float*)d_in[14];
  const float* g2  = (const float*)d_in[15];
  const float* be2 = (const float*)d_in[16];
  const int* batch = (const int*)d_in[17];
  const int* ei    = (const int*)d_in[18];
  int N = in_sizes[0] / HD;       // 6400
  int E = in_sizes[18] / 2;       // 102400
  int MD = B_G * S_MAX;           // 8192 dense rows

  // workspace layout (~50 MB):
  //   [0,8MB)    x  -> later attO -> later ff2   (aliased; each dead before next use)
  //   [8,16MB)   Q  -> later hatt
  //   [16,24MB)  K  -> later h1
  //   [24MB,+512KB) adj ; then offs(128B) ; rowmap(25.6KB)
  //   [25MB,+26.2MB) ff1
  char* ws = (char*)d_ws;
  float* x    = (float*)(ws);
  float* Qm   = (float*)(ws + ((size_t)8 << 20));
  float* Km   = (float*)(ws + ((size_t)16 << 20));
  u32*   adj  = (u32*)  (ws + ((size_t)24 << 20));
  int*   offs = (int*)  (ws + ((size_t)24 << 20) + ((size_t)512 << 10));
  int*   rmap = (int*)  (ws + ((size_t)24 << 20) + ((size_t)512 << 10) + 256);
  float* ff1  = (float*)(ws + ((size_t)25 << 20));
  float* attO = x;
  float* hatt = Qm;
  float* h1   = Km;
  float* ff2  = x;

  hipMemsetAsync(x, 0, (size_t)MD * HD * sizeof(float), stream);
  hipMemsetAsync(adj, 0, (size_t)B_G * S_MAX * ADJW * sizeof(u32), stream);
  k_offsets<<<1, 32, 0, stream>>>(batch, N, offs);
  k_scatter<<<N, 64, 0, stream>>>(h, batch, offs, x, rmap);
  k_adj<<<(E + 255) / 256, 256, 0, stream>>>(ei, E, batch, offs, adj);

  k_gemm<false><<<dim3(MD / 64, HD / 64), 256, 0, stream>>>(x, Wq, bq, Qm, HD, HD, nullptr);
  k_gemm<false><<<dim3(MD / 64, HD / 64), 256, 0, stream>>>(x, Wk, bk, Km, HD, HD, nullptr);

  k_attn<<<B_G * NH * 4, 256, 0, stream>>>(Qm, Km, adj, offs, attO);

  k_gemm<false><<<dim3(N / 64, HD / 64), 256, 0, stream>>>(attO, Wo, bo, hatt, HD, HD, rmap);
  k_ln<<<N, 256, 0, stream>>>(hatt, h, g1, be1, h1);
  k_gemm<true><<<dim3(N / 64, FFD / 64), 256, 0, stream>>>(h1, W1, b1, ff1, FFD, HD, nullptr);
  k_gemm<false><<<dim3(N / 64, HD / 64), 256, 0, stream>>>(ff1, W2, b2, ff2, HD, FFD, nullptr);
  k_ln<<<N, 256, 0, stream>>>(ff2, h1, g2, be2, (float*)d_out);
}

// Round 3
// 125.104 us; speedup vs baseline: 3.0269x; 3.0269x over previous
//
#include <hip/hip_runtime.h>
#include <math.h>

typedef unsigned int u32;
typedef unsigned short ushort_t;
typedef __attribute__((ext_vector_type(8))) short short8;
typedef __attribute__((ext_vector_type(4))) float f32x4;
typedef __attribute__((ext_vector_type(16))) float f32x16;

#define B_G 16
#define S_MAX 512
#define NH 8
#define DH 32
#define HD 256
#define FFD 1024
#define ADJW 16            // u32 words per adjacency row (512 bits)

// ---------- bf16 helpers (RNE) ----------
__device__ __forceinline__ ushort_t f2bf(float f) {
  u32 u = __float_as_uint(f);
  u += 0x7fffu + ((u >> 16) & 1u);
  return (ushort_t)(u >> 16);
}

__device__ __forceinline__ int swz(int r) { return (r ^ (r >> 2)) & 3; }

// async global->LDS, 16B per lane
__device__ __forceinline__ void gll16(const void* g, void* l) {
  __builtin_amdgcn_global_load_lds(
      (const __attribute__((address_space(1))) unsigned int*)g,
      (__attribute__((address_space(3))) unsigned int*)l, 16, 0, 0);
}

// ---------- graph offsets via binary search ----------
__global__ void k_offsets(const int* __restrict__ batch, int N, int* __restrict__ offs) {
  int g = threadIdx.x;
  if (g > B_G) return;
  if (g == B_G) { offs[B_G] = N; return; }
  int lo = 0, hi = N;
  while (lo < hi) { int mid = (lo + hi) >> 1; if (batch[mid] < g) lo = mid + 1; else hi = mid; }
  offs[g] = lo;
}

// ---------- scatter nodes into dense bf16 [B*S, H] (pre-zeroed) ----------
__global__ void k_scatter(const float* __restrict__ h, const int* __restrict__ batch,
                          const int* __restrict__ offs, ushort_t* __restrict__ xb) {
  int i = blockIdx.x;
  int c = threadIdx.x;          // 64 threads x 4 elements
  int b = batch[i];
  int row = b * S_MAX + (i - offs[b]);
  float4 v = ((const float4*)(h + (size_t)i * HD))[c];
  u32 lo = (u32)f2bf(v.x) | ((u32)f2bf(v.y) << 16);
  u32 hi = (u32)f2bf(v.z) | ((u32)f2bf(v.w) << 16);
  uint2 pk = {lo, hi};
  *(uint2*)(xb + (size_t)row * HD + c * 4) = pk;
}

// ---------- adjacency bitmask: bit set => edge => p=0 ----------
__global__ void k_adj(const int* __restrict__ ei, int E, const int* __restrict__ batch,
                      const int* __restrict__ offs, u32* __restrict__ adj) {
  int e = blockIdx.x * 256 + threadIdx.x;
  if (e >= E) return;
  int s = ei[e], d = ei[E + e];
  int b = batch[s];
  int o = offs[b];
  int ps = s - o, pd = d - o;
  atomicOr(&adj[(b * S_MAX + ps) * ADJW + (pd >> 5)], 1u << (pd & 31));
}

// ---------- weight fp32 -> bf16 (5 segments, block-range dispatch) ----------
__global__ __launch_bounds__(256) void k_cvt5(
    const float* __restrict__ a, const float* __restrict__ b, const float* __restrict__ c,
    const float* __restrict__ d, const float* __restrict__ e,
    ushort_t* __restrict__ oa, ushort_t* __restrict__ ob, ushort_t* __restrict__ oc,
    ushort_t* __restrict__ od, ushort_t* __restrict__ oe) {
  int blk = blockIdx.x;
  const float* src; ushort_t* dst; int off;
  if (blk < 32)       { src = a; dst = oa; off = blk; }
  else if (blk < 64)  { src = b; dst = ob; off = blk - 32; }
  else if (blk < 96)  { src = c; dst = oc; off = blk - 64; }
  else if (blk < 224) { src = d; dst = od; off = blk - 96; }
  else                { src = e; dst = oe; off = blk - 224; }
  size_t i = (size_t)off * 2048 + threadIdx.x * 8;
  float4 v0 = *(const float4*)&src[i];
  float4 v1 = *(const float4*)&src[i + 4];
  uint4 pk;
  pk.x = (u32)f2bf(v0.x) | ((u32)f2bf(v0.y) << 16);
  pk.y = (u32)f2bf(v0.z) | ((u32)f2bf(v0.w) << 16);
  pk.z = (u32)f2bf(v1.x) | ((u32)f2bf(v1.y) << 16);
  pk.w = (u32)f2bf(v1.z) | ((u32)f2bf(v1.w) << 16);
  *(uint4*)&dst[i] = pk;
}

// ---------- MFMA bf16 GEMM: C[m,n] = sum_k A[m,k]*W[n,k] + bias[n] ----------
// 128x128 tile, BK=32, 4 waves each 64x64 (4x4 frags of 16x16x32).
// LDS [row][chunk^swz(row)] (chunk=8 bf16=16B); global_load_lds keeps sources
// coalesced by permuting chunk order per row; frag reads ds_read_b128 ~2-way.
template<bool RELU, bool OUTBF>
__global__ __launch_bounds__(256) void k_mgemm(const ushort_t* __restrict__ A,
    const ushort_t* __restrict__ W, const float* __restrict__ bias,
    void* __restrict__ Cout, int Ncols, int Kdim) {
  __shared__ __align__(16) ushort_t As[128 * 32];
  __shared__ __align__(16) ushort_t Bs[128 * 32];
  int tid = threadIdx.x;
  int wid = tid >> 6, lane = tid & 63;
  int wm = wid >> 1, wn = wid & 1;
  int arow0 = blockIdx.x * 128, bcol0 = blockIdx.y * 128;

  int s1 = tid, s2 = tid + 256;
  int r1 = s1 >> 2, c1 = (s1 & 3) ^ swz(r1);
  int r2 = s2 >> 2, c2 = (s2 & 3) ^ swz(r2);
  const ushort_t* gA1 = A + (size_t)(arow0 + r1) * Kdim + c1 * 8;
  const ushort_t* gA2 = A + (size_t)(arow0 + r2) * Kdim + c2 * 8;
  const ushort_t* gB1 = W + (size_t)(bcol0 + r1) * Kdim + c1 * 8;
  const ushort_t* gB2 = W + (size_t)(bcol0 + r2) * Kdim + c2 * 8;
  ushort_t* lA1 = &As[(wid * 64) * 8];
  ushort_t* lA2 = &As[(256 + wid * 64) * 8];
  ushort_t* lB1 = &Bs[(wid * 64) * 8];
  ushort_t* lB2 = &Bs[(256 + wid * 64) * 8];

  f32x4 acc[4][4];
  #pragma unroll
  for (int i = 0; i < 4; i++)
    #pragma unroll
    for (int j = 0; j < 4; j++) { f32x4 z = {0.f, 0.f, 0.f, 0.f}; acc[i][j] = z; }

  for (int k0 = 0; k0 < Kdim; k0 += 32) {
    __syncthreads();
    gll16(gA1 + k0, lA1); gll16(gA2 + k0, lA2);
    gll16(gB1 + k0, lB1); gll16(gB2 + k0, lB2);
    asm volatile("s_waitcnt vmcnt(0)" ::: "memory");
    __syncthreads();
    short8 af[4], bf[4];
    #pragma unroll
    for (int i = 0; i < 4; i++) {
      int row = wm * 64 + i * 16 + (lane & 15);
      int ck = (lane >> 4) ^ swz(row);
      af[i] = *(const short8*)&As[row * 32 + ck * 8];
    }
    #pragma unroll
    for (int j = 0; j < 4; j++) {
      int row = wn * 64 + j * 16 + (lane & 15);
      int ck = (lane >> 4) ^ swz(row);
      bf[j] = *(const short8*)&Bs[row * 32 + ck * 8];
    }
    #pragma unroll
    for (int i = 0; i < 4; i++)
      #pragma unroll
      for (int j = 0; j < 4; j++)
        acc[i][j] = __builtin_amdgcn_mfma_f32_16x16x32_bf16(af[i], bf[j], acc[i][j], 0, 0, 0);
  }

  // epilogue: C row=(lane>>4)*4+reg, col=lane&15 (HW-verified layout)
  float bj[4];
  #pragma unroll
  for (int j = 0; j < 4; j++)
    bj[j] = bias[bcol0 + wn * 64 + j * 16 + (lane & 15)];
  #pragma unroll
  for (int i = 0; i < 4; i++) {
    #pragma unroll
    for (int r = 0; r < 4; r++) {
      int row = arow0 + wm * 64 + i * 16 + (lane >> 4) * 4 + r;
      size_t base = (size_t)row * Ncols + bcol0 + wn * 64 + (lane & 15);
      #pragma unroll
      for (int j = 0; j < 4; j++) {
        float v = acc[i][j][r] + bj[j];
        if (RELU) v = fmaxf(v, 0.f);
        if (OUTBF) ((ushort_t*)Cout)[base + j * 16] = f2bf(v);
        else       ((float*)Cout)[base + j * 16] = v;
      }
    }
  }
}

// ---------- fused masked attention, MFMA 32x32x16, swapped operands ----------
// Block = (b, head, q-quarter of 128 rows); 4 waves x 32 q-rows.
// S^T tile = mfma(K_frag, Q_frag) -> lane owns q-column (softmax lane-local,
// no max subtraction needed: logits are O(1)). P^T via per-wave LDS roundtrip,
// O^T = mfma(Kt_frag, P_frag) with V == K (faithful to reference).
__global__ __launch_bounds__(256) void k_attn(const ushort_t* __restrict__ qkb,
    const u32* __restrict__ adj, const int* __restrict__ offs,
    ushort_t* __restrict__ attOb) {
  int bid = blockIdx.x;               // b(4b) | h(3b) | qtr(2b)
  int qtr = bid & 3, hh = (bid >> 2) & 7, b = bid >> 5;
  int nstart = offs[b], len = offs[b + 1] - nstart;
  int q0blk = qtr * 128;
  if (q0blk >= len) return;

  __shared__ __align__(16) ushort_t K_lds[4 * 512 * 8];    // [kchunk][t][8] 32KB
  __shared__ __align__(16) ushort_t Kt_lds[64 * 32 * 8];   // [tchunk][d][8] 32KB
  __shared__ __align__(16) ushort_t P_lds[4 * 4 * 32 * 8]; // [wave][g][q][8] 8KB

  int tid = threadIdx.x;
  // phase 1: K rows (cols 256.. of qkb) -> K_lds chunk-planar
  {
    const ushort_t* kg = qkb + (size_t)(b * S_MAX) * 512 + 256 + hh * 32;
    for (int t = tid; t < 512; t += 256) {
      const uint4* src = (const uint4*)(kg + (size_t)t * 512);
      uint4 v0 = src[0], v1 = src[1], v2 = src[2], v3 = src[3];
      *(uint4*)&K_lds[0 * 4096 + t * 8] = v0;
      *(uint4*)&K_lds[1 * 4096 + t * 8] = v1;
      *(uint4*)&K_lds[2 * 4096 + t * 8] = v2;
      *(uint4*)&K_lds[3 * 4096 + t * 8] = v3;
    }
  }
  __syncthreads();
  // phase 2: transpose K -> Kt  (Kt[tc][d][j] = K[tc*8+j][d])
  {
    int d = tid & 31, tg = tid >> 5;
    int cc = d >> 3, e = d & 7;
    for (int i = 0; i < 8; i++) {
      int t0 = tg * 64 + i * 8;
      u32 w0 = (u32)K_lds[cc * 4096 + (t0 + 0) * 8 + e] | ((u32)K_lds[cc * 4096 + (t0 + 1) * 8 + e] << 16);
      u32 w1 = (u32)K_lds[cc * 4096 + (t0 + 2) * 8 + e] | ((u32)K_lds[cc * 4096 + (t0 + 3) * 8 + e] << 16);
      u32 w2 = (u32)K_lds[cc * 4096 + (t0 + 4) * 8 + e] | ((u32)K_lds[cc * 4096 + (t0 + 5) * 8 + e] << 16);
      u32 w3 = (u32)K_lds[cc * 4096 + (t0 + 6) * 8 + e] | ((u32)K_lds[cc * 4096 + (t0 + 7) * 8 + e] << 16);
      uint4 pk = {w0, w1, w2, w3};
      *(uint4*)&Kt_lds[(t0 >> 3) * 256 + d * 8] = pk;
    }
  }
  __syncthreads();

  int w = tid >> 6, lane = tid & 63;
  int q0w = q0blk + w * 32;
  if (q0w >= len) return;   // no barriers below: safe divergence

  int lq = lane & 31, hf = lane >> 5;
  int q_abs = q0w + lq;
  const float SCALE = 0.17677669529663687f;  // 1/sqrt(32)

  size_t qrow = (size_t)(b * S_MAX + q_abs) * 512 + hh * 32;
  short8 qf0 = *(const short8*)(qkb + qrow + hf * 8);
  short8 qf1 = *(const short8*)(qkb + qrow + 16 + hf * 8);

  const uint4* ap = (const uint4*)(adj + (size_t)(b * S_MAX + q_abs) * ADJW);
  uint4 a0 = ap[0], a1 = ap[1], a2 = ap[2], a3 = ap[3];
  u32 aw[16] = {a0.x, a0.y, a0.z, a0.w, a1.x, a1.y, a1.z, a1.w,
                a2.x, a2.y, a2.z, a2.w, a3.x, a3.y, a3.z, a3.w};

  f32x16 oacc = {0.f,0.f,0.f,0.f,0.f,0.f,0.f,0.f,0.f,0.f,0.f,0.f,0.f,0.f,0.f,0.f};
  float lsum = 0.f;

  #pragma unroll
  for (int tt = 0; tt < 16; tt++) {
    int t0 = tt * 32;
    // QK^T (swapped): D[t][q]
    short8 ka0 = *(const short8*)&K_lds[hf * 4096 + (t0 + lq) * 8];
    short8 ka1 = *(const short8*)&K_lds[(2 + hf) * 4096 + (t0 + lq) * 8];
    f32x16 sc = {0.f,0.f,0.f,0.f,0.f,0.f,0.f,0.f,0.f,0.f,0.f,0.f,0.f,0.f,0.f,0.f};
    sc = __builtin_amdgcn_mfma_f32_32x32x16_bf16(ka0, qf0, sc, 0, 0, 0);
    sc = __builtin_amdgcn_mfma_f32_32x32x16_bf16(ka1, qf1, sc, 0, 0, 0);
    // mask + exp (edges -> 0), accumulate denominator
    u32 word = aw[tt];
    float p[16];
    #pragma unroll
    for (int r = 0; r < 16; r++) {
      int tb = (r & 3) + 8 * (r >> 2) + 4 * hf;   // t-local of this reg
      float pe = __expf(sc[r] * SCALE);
      p[r] = ((word >> tb) & 1u) ? 0.f : pe;
      lsum += p[r];
    }
    // P^T -> LDS (per-wave), packed 4 consecutive t per b64
    #pragma unroll
    for (int g = 0; g < 4; g++) {
      u32 lo = (u32)f2bf(p[4 * g]) | ((u32)f2bf(p[4 * g + 1]) << 16);
      u32 hi = (u32)f2bf(p[4 * g + 2]) | ((u32)f2bf(p[4 * g + 3]) << 16);
      uint2 pk = {lo, hi};
      *(uint2*)&P_lds[w * 1024 + g * 256 + lq * 8 + hf * 4] = pk;
    }
    // PV: O^T[d][q] += V^T x P^T  (V == K)
    short8 va0 = *(const short8*)&Kt_lds[(t0 / 8 + hf) * 256 + lq * 8];
    short8 va1 = *(const short8*)&Kt_lds[(t0 / 8 + 2 + hf) * 256 + lq * 8];
    short8 pb0 = *(const short8*)&P_lds[w * 1024 + hf * 256 + lq * 8];
    short8 pb1 = *(const short8*)&P_lds[w * 1024 + (2 + hf) * 256 + lq * 8];
    oacc = __builtin_amdgcn_mfma_f32_32x32x16_bf16(va0, pb0, oacc, 0, 0, 0);
    oacc = __builtin_amdgcn_mfma_f32_32x32x16_bf16(va1, pb1, oacc, 0, 0, 0);
  }

  float ltot = lsum + __shfl_xor(lsum, 32, 64);
  float inv = 1.f / ltot;
  if (q_abs < len) {
    int node = nstart + q_abs;
    ushort_t* op = attOb + (size_t)node * HD + hh * DH;
    #pragma unroll
    for (int g = 0; g < 4; g++) {
      float v0 = oacc[4 * g] * inv, v1 = oacc[4 * g + 1] * inv;
      float v2 = oacc[4 * g + 2] * inv, v3 = oacc[4 * g + 3] * inv;
      u32 lo = (u32)f2bf(v0) | ((u32)f2bf(v1) << 16);
      u32 hi = (u32)f2bf(v2) | ((u32)f2bf(v3) << 16);
      uint2 pk = {lo, hi};
      *(uint2*)(op + g * 8 + hf * 4) = pk;   // d = 8g + 4hf + 0..3
    }
  }
}

// ---------- LayerNorm(a + res) * g + be; optional bf16 dual-store ----------
template<bool BF>
__global__ __launch_bounds__(256) void k_ln(const float* __restrict__ a,
    const float* __restrict__ res, const float* __restrict__ g,
    const float* __restrict__ be, float* __restrict__ out, ushort_t* __restrict__ outb) {
  int n = blockIdx.x, c = threadIdx.x;
  float v = a[(size_t)n * HD + c] + res[(size_t)n * HD + c];
  float s = v, q = v * v;
  #pragma unroll
  for (int o = 1; o < 64; o <<= 1) { s += __shfl_xor(s, o, 64); q += __shfl_xor(q, o, 64); }
  __shared__ float red[8];
  int w = c >> 6, lane = c & 63;
  if (lane == 0) { red[w] = s; red[4 + w] = q; }
  __syncthreads();
  s = red[0] + red[1] + red[2] + red[3];
  q = red[4] + red[5] + red[6] + red[7];
  float mu = s * (1.f / HD);
  float var = q * (1.f / HD) - mu * mu;
  float inv = rsqrtf(var + 1e-5f);
  float o_ = (v - mu) * inv * g[c] + be[c];
  out[(size_t)n * HD + c] = o_;
  if (BF) outb[(size_t)n * HD + c] = f2bf(o_);
}

extern "C" void kernel_launch(void* const* d_in, const int* in_sizes, int n_in,
                              void* d_out, int out_size, void* d_ws, size_t ws_size,
                              hipStream_t stream) {
  const float* h   = (const float*)d_in[0];
  const float* Wq  = (const float*)d_in[1];
  const float* bq  = (const float*)d_in[2];
  const float* Wk  = (const float*)d_in[3];
  const float* bk  = (const float*)d_in[4];
  // d_in[5], d_in[6] (Wv, bv) unused: reference V uses the K projection
  const float* Wo  = (const float*)d_in[7];
  const float* bo  = (const float*)d_in[8];
  const float* W1  = (const float*)d_in[9];
  const float* b1  = (const float*)d_in[10];
  const float* W2  = (const float*)d_in[11];
  const float* b2  = (const float*)d_in[12];
  const float* g1  = (const float*)d_in[13];
  const float* be1 = (const float*)d_in[14];
  const float* g2  = (const float*)d_in[15];
  const float* be2 = (const float*)d_in[16];
  const int* batch = (const int*)d_in[17];
  const int* ei    = (const int*)d_in[18];
  int N = in_sizes[0] / HD;       // 6400
  int E = in_sizes[18] / 2;       // 102400
  int MD = B_G * S_MAX;           // 8192

  // workspace layout (~38.3 MB)
  char* ws = (char*)d_ws;
  ushort_t* xb    = (ushort_t*)(ws);                              // 4MB  [8192,256] bf16
  ushort_t* attOb = xb;                                           // alias (xb dead after QK gemm)
  ushort_t* qkb   = (ushort_t*)(ws + ((size_t)4 << 20));          // 8MB  [8192,512] bf16
  float*    hatt  = (float*)(ws + ((size_t)4 << 20));             // alias (qkb dead after attn)
  float*    ff2   = hatt;                                         // alias (hatt dead after LN1)
  float*    h1    = (float*)(ws + ((size_t)12 << 20));            // 6.4MB
  ushort_t* h1b   = (ushort_t*)(ws + ((size_t)19 << 20));         // 3.2MB
  ushort_t* ff1b  = (ushort_t*)(ws + ((size_t)23 << 20));         // 12.8MB
  char* wbase = ws + ((size_t)36 << 20);
  ushort_t* Wqkb = (ushort_t*)(wbase);                            // 256KB [512,256]
  ushort_t* Wob  = (ushort_t*)(wbase + (256 << 10));              // 128KB
  ushort_t* W1b  = (ushort_t*)(wbase + (384 << 10));              // 512KB [1024,256]
  ushort_t* W2b  = (ushort_t*)(wbase + (896 << 10));              // 512KB [256,1024]
  float*    bqk  = (float*)(wbase + (1408 << 10));                // 4KB  [512]
  u32*      adj  = (u32*)(wbase + (1536 << 10));                  // 512KB
  int*      offs = (int*)(ws + ((size_t)38 << 20));               // 128B

  hipMemsetAsync(xb, 0, (size_t)MD * HD * 2, stream);
  hipMemsetAsync(adj, 0, (size_t)B_G * S_MAX * ADJW * 4, stream);
  k_offsets<<<1, 32, 0, stream>>>(batch, N, offs);
  k_scatter<<<N, 64, 0, stream>>>(h, batch, offs, xb);
  k_adj<<<(E + 255) / 256, 256, 0, stream>>>(ei, E, batch, offs, adj);
  k_cvt5<<<352, 256, 0, stream>>>(Wq, Wk, Wo, W1, W2,
                                  Wqkb, Wqkb + 65536, Wob, W1b, W2b);
  hipMemcpyAsync(bqk, bq, HD * sizeof(float), hipMemcpyDeviceToDevice, stream);
  hipMemcpyAsync(bqk + HD, bk, HD * sizeof(float), hipMemcpyDeviceToDevice, stream);

  // fused Q|K projection: [8192,256] x [512,256]^T -> [8192,512] bf16
  k_mgemm<false, true><<<dim3(MD / 128, 4), 256, 0, stream>>>(xb, Wqkb, bqk, qkb, 512, HD);
  // attention -> compact [6400,256] bf16
  k_attn<<<B_G * NH * 4, 256, 0, stream>>>(qkb, adj, offs, attOb);
  // out-proj -> fp32
  k_mgemm<false, false><<<dim3(N / 128, 2), 256, 0, stream>>>(attOb, Wob, bo, hatt, HD, HD);
  k_ln<true><<<N, 256, 0, stream>>>(hatt, h, g1, be1, h1, h1b);
  // FFN
  k_mgemm<true, true><<<dim3(N / 128, 8), 256, 0, stream>>>(h1b, W1b, b1, ff1b, FFD, HD);
  k_mgemm<false, false><<<dim3(N / 128, 2), 256, 0, stream>>>(ff1b, W2b, b2, ff2, HD, FFD);
  k_ln<false><<<N, 256, 0, stream>>>(ff2, h1, g2, be2, (float*)d_out, nullptr);
}

// Round 4
// 107.818 us; speedup vs baseline: 3.5122x; 1.1603x over previous
//
#include <hip/hip_runtime.h>
#include <math.h>

typedef unsigned int u32;
typedef unsigned short ushort_t;
typedef __attribute__((ext_vector_type(8))) short short8;
typedef __attribute__((ext_vector_type(4))) float f32x4;
typedef __attribute__((ext_vector_type(16))) float f32x16;

#define B_G 16
#define S_MAX 512
#define NH 8
#define DH 32
#define HD 256
#define FFD 1024
#define ADJW 16            // u32 words per adjacency row (512 bits)

// ---------- bf16 helpers (RNE) ----------
__device__ __forceinline__ ushort_t f2bf(float f) {
  u32 u = __float_as_uint(f);
  u += 0x7fffu + ((u >> 16) & 1u);
  return (ushort_t)(u >> 16);
}

// async global->LDS, 16B per lane
__device__ __forceinline__ void gll16(const void* g, void* l) {
  __builtin_amdgcn_global_load_lds(
      (const __attribute__((address_space(1))) unsigned int*)g,
      (__attribute__((address_space(3))) unsigned int*)l, 16, 0, 0);
}

// ---------- offsets (binary search) + bias concat ----------
__global__ __launch_bounds__(512) void k_offsets(const int* __restrict__ batch, int N,
    int* __restrict__ offs, const float* __restrict__ bq, const float* __restrict__ bk,
    float* __restrict__ bqk) {
  int t = threadIdx.x;
  bqk[t] = (t < HD) ? bq[t] : bk[t - HD];
  if (t > B_G) return;
  if (t == B_G) { offs[B_G] = N; return; }
  int lo = 0, hi = N;
  while (lo < hi) { int mid = (lo + hi) >> 1; if (batch[mid] < t) lo = mid + 1; else hi = mid; }
  offs[t] = lo;
}

// ---------- mega prep: dense-scatter+zero | adjacency | weight cvt ----------
// blocks 0..2047: 4 dense rows each (scatter h or zero pad)
// blocks 2048..2447: edges -> adj atomicOr (adj pre-zeroed by memset)
// blocks 2448..2799: fp32->bf16 weight convert (5 segments)
__global__ __launch_bounds__(256) void k_mega(
    const float* __restrict__ h, const int* __restrict__ offs, ushort_t* __restrict__ xb,
    const int* __restrict__ ei, int E, const int* __restrict__ batch, u32* __restrict__ adj,
    const float* __restrict__ wa, const float* __restrict__ wb, const float* __restrict__ wc,
    const float* __restrict__ wd, const float* __restrict__ we,
    ushort_t* __restrict__ oa, ushort_t* __restrict__ ob, ushort_t* __restrict__ oc,
    ushort_t* __restrict__ od, ushort_t* __restrict__ oe) {
  int blk = blockIdx.x, tid = threadIdx.x;
  if (blk < 2048) {
    int row = blk * 4 + (tid >> 6);
    int c = tid & 63;
    int b = row >> 9, pos = row & 511;
    int len = offs[b + 1] - offs[b];
    uint2 pk = {0u, 0u};
    if (pos < len) {
      int node = offs[b] + pos;
      float4 v = ((const float4*)(h + (size_t)node * HD))[c];
      pk.x = (u32)f2bf(v.x) | ((u32)f2bf(v.y) << 16);
      pk.y = (u32)f2bf(v.z) | ((u32)f2bf(v.w) << 16);
    }
    *(uint2*)(xb + (size_t)row * HD + c * 4) = pk;
  } else if (blk < 2448) {
    int e = (blk - 2048) * 256 + tid;
    if (e >= E) return;
    int s = ei[e], d = ei[E + e];
    int b = batch[s];
    int o = offs[b];
    atomicOr(&adj[(b * S_MAX + (s - o)) * ADJW + ((d - o) >> 5)], 1u << ((d - o) & 31));
  } else {
    int bb = blk - 2448;
    const float* src; ushort_t* dst; int off;
    if (bb < 32)       { src = wa; dst = oa; off = bb; }
    else if (bb < 64)  { src = wb; dst = ob; off = bb - 32; }
    else if (bb < 96)  { src = wc; dst = oc; off = bb - 64; }
    else if (bb < 224) { src = wd; dst = od; off = bb - 96; }
    else               { src = we; dst = oe; off = bb - 224; }
    size_t i = (size_t)off * 2048 + tid * 8;
    float4 v0 = *(const float4*)&src[i];
    float4 v1 = *(const float4*)&src[i + 4];
    uint4 pk;
    pk.x = (u32)f2bf(v0.x) | ((u32)f2bf(v0.y) << 16);
    pk.y = (u32)f2bf(v0.z) | ((u32)f2bf(v0.w) << 16);
    pk.z = (u32)f2bf(v1.x) | ((u32)f2bf(v1.y) << 16);
    pk.w = (u32)f2bf(v1.z) | ((u32)f2bf(v1.w) << 16);
    *(uint4*)&dst[i] = pk;
  }
}

// ---------- MFMA bf16 GEMM, 128x128 tile, BK=64 ----------
// LDS element (r,k) at r*64 + ((k/8)^(r&7))*8 + k%8 via pre-swizzled global src.
template<bool RELU, bool OUTBF>
__global__ __launch_bounds__(256) void k_mgemm(const ushort_t* __restrict__ A,
    const ushort_t* __restrict__ W, const float* __restrict__ bias,
    void* __restrict__ Cout, int Ncols, int Kdim) {
  __shared__ __align__(16) ushort_t As[128 * 64];
  __shared__ __align__(16) ushort_t Bs[128 * 64];
  int tid = threadIdx.x;
  int wid = tid >> 6, lane = tid & 63;
  int wm = wid >> 1, wn = wid & 1;
  int arow0 = blockIdx.x * 128, bcol0 = blockIdx.y * 128;

  const ushort_t* gA[4]; const ushort_t* gB[4];
  ushort_t* lA[4]; ushort_t* lB[4];
  #pragma unroll
  for (int i = 0; i < 4; i++) {
    int s = i * 256 + tid;
    int r = s >> 3, c = (s & 7) ^ (r & 7);
    gA[i] = A + (size_t)(arow0 + r) * Kdim + c * 8;
    gB[i] = W + (size_t)(bcol0 + r) * Kdim + c * 8;
    lA[i] = &As[(i * 256 + wid * 64) * 8];
    lB[i] = &Bs[(i * 256 + wid * 64) * 8];
  }

  f32x4 acc[4][4];
  #pragma unroll
  for (int i = 0; i < 4; i++)
    #pragma unroll
    for (int j = 0; j < 4; j++) { f32x4 z = {0.f, 0.f, 0.f, 0.f}; acc[i][j] = z; }

  for (int k0 = 0; k0 < Kdim; k0 += 64) {
    __syncthreads();
    #pragma unroll
    for (int i = 0; i < 4; i++) { gll16(gA[i] + k0, lA[i]); gll16(gB[i] + k0, lB[i]); }
    asm volatile("s_waitcnt vmcnt(0)" ::: "memory");
    __syncthreads();
    #pragma unroll
    for (int ks = 0; ks < 2; ks++) {
      short8 af[4], bf[4];
      #pragma unroll
      for (int i = 0; i < 4; i++) {
        int row = wm * 64 + i * 16 + (lane & 15);
        int ck = (ks * 4 + (lane >> 4)) ^ (row & 7);
        af[i] = *(const short8*)&As[row * 64 + ck * 8];
      }
      #pragma unroll
      for (int j = 0; j < 4; j++) {
        int row = wn * 64 + j * 16 + (lane & 15);
        int ck = (ks * 4 + (lane >> 4)) ^ (row & 7);
        bf[j] = *(const short8*)&Bs[row * 64 + ck * 8];
      }
      #pragma unroll
      for (int i = 0; i < 4; i++)
        #pragma unroll
        for (int j = 0; j < 4; j++)
          acc[i][j] = __builtin_amdgcn_mfma_f32_16x16x32_bf16(af[i], bf[j], acc[i][j], 0, 0, 0);
    }
  }

  float bj[4];
  #pragma unroll
  for (int j = 0; j < 4; j++)
    bj[j] = bias[bcol0 + wn * 64 + j * 16 + (lane & 15)];
  #pragma unroll
  for (int i = 0; i < 4; i++) {
    #pragma unroll
    for (int r = 0; r < 4; r++) {
      int row = arow0 + wm * 64 + i * 16 + (lane >> 4) * 4 + r;
      size_t base = (size_t)row * Ncols + bcol0 + wn * 64 + (lane & 15);
      #pragma unroll
      for (int j = 0; j < 4; j++) {
        float v = acc[i][j][r] + bj[j];
        if (RELU) v = fmaxf(v, 0.f);
        if (OUTBF) ((ushort_t*)Cout)[base + j * 16] = f2bf(v);
        else       ((float*)Cout)[base + j * 16] = v;
      }
    }
  }
}

// ---------- MFMA GEMM (M-tile 128 x all-256 cols) + residual + LayerNorm ----------
// 512 threads = 8 waves: wm=wid>>1 (32 rows), wn=wid&1 (128 cols). BK=64.
// out = LN(A*W^T + bias + R) * gamma + beta; fp32 out + optional bf16 copy.
template<bool OUTBF>
__global__ __launch_bounds__(512) void k_gemm_ln(const ushort_t* __restrict__ A,
    const ushort_t* __restrict__ W, const float* __restrict__ bias,
    const float* __restrict__ R, const float* __restrict__ gamma,
    const float* __restrict__ beta, float* __restrict__ outF,
    ushort_t* __restrict__ outB, int Kdim) {
  __shared__ __align__(16) ushort_t As[128 * 64];   // 16KB
  __shared__ __align__(16) ushort_t Bs[256 * 64];   // 32KB
  __shared__ float red[128][4];                     // [row][wn*2 + {sum,sq}]
  int tid = threadIdx.x;
  int wid = tid >> 6, lane = tid & 63;
  int wm = wid >> 1, wn = wid & 1;
  int row0 = blockIdx.x * 128;

  const ushort_t* gA[2]; ushort_t* lA[2];
  const ushort_t* gB[4]; ushort_t* lB[4];
  #pragma unroll
  for (int i = 0; i < 2; i++) {
    int s = i * 512 + tid;
    int r = s >> 3, c = (s & 7) ^ (r & 7);
    gA[i] = A + (size_t)(row0 + r) * Kdim + c * 8;
    lA[i] = &As[(i * 512 + wid * 64) * 8];
  }
  #pragma unroll
  for (int i = 0; i < 4; i++) {
    int s = i * 512 + tid;
    int r = s >> 3, c = (s & 7) ^ (r & 7);
    gB[i] = W + (size_t)r * Kdim + c * 8;
    lB[i] = &Bs[(i * 512 + wid * 64) * 8];
  }

  f32x4 acc[2][8];
  #pragma unroll
  for (int m = 0; m < 2; m++)
    #pragma unroll
    for (int n = 0; n < 8; n++) { f32x4 z = {0.f, 0.f, 0.f, 0.f}; acc[m][n] = z; }

  for (int k0 = 0; k0 < Kdim; k0 += 64) {
    __syncthreads();
    #pragma unroll
    for (int i = 0; i < 2; i++) gll16(gA[i] + k0, lA[i]);
    #pragma unroll
    for (int i = 0; i < 4; i++) gll16(gB[i] + k0, lB[i]);
    asm volatile("s_waitcnt vmcnt(0)" ::: "memory");
    __syncthreads();
    #pragma unroll
    for (int ks = 0; ks < 2; ks++) {
      short8 af[2], bf[8];
      #pragma unroll
      for (int m = 0; m < 2; m++) {
        int row = wm * 32 + m * 16 + (lane & 15);
        int ck = (ks * 4 + (lane >> 4)) ^ (row & 7);
        af[m] = *(const short8*)&As[row * 64 + ck * 8];
      }
      #pragma unroll
      for (int n = 0; n < 8; n++) {
        int row = wn * 128 + n * 16 + (lane & 15);
        int ck = (ks * 4 + (lane >> 4)) ^ (row & 7);
        bf[n] = *(const short8*)&Bs[row * 64 + ck * 8];
      }
      #pragma unroll
      for (int m = 0; m < 2; m++)
        #pragma unroll
        for (int n = 0; n < 8; n++)
          acc[m][n] = __builtin_amdgcn_mfma_f32_16x16x32_bf16(af[m], bf[n], acc[m][n], 0, 0, 0);
    }
  }

  int colb = wn * 128 + (lane & 15);
  float bc[8], gm[8], bt[8];
  #pragma unroll
  for (int n = 0; n < 8; n++) {
    bc[n] = bias[colb + n * 16];
    gm[n] = gamma[colb + n * 16];
    bt[n] = beta[colb + n * 16];
  }
  // v = acc + bias + residual; per-row partial sums over this wave's 128 cols
  #pragma unroll
  for (int m = 0; m < 2; m++) {
    #pragma unroll
    for (int r = 0; r < 4; r++) {
      int row_l = wm * 32 + m * 16 + (lane >> 4) * 4 + r;
      const float* Rrow = R + (size_t)(row0 + row_l) * HD;
      float s = 0.f, q = 0.f;
      #pragma unroll
      for (int n = 0; n < 8; n++) {
        float v = acc[m][n][r] + bc[n] + Rrow[colb + n * 16];
        acc[m][n][r] = v;
        s += v; q += v * v;
      }
      #pragma unroll
      for (int o = 1; o < 16; o <<= 1) { s += __shfl_xor(s, o, 64); q += __shfl_xor(q, o, 64); }
      if ((lane & 15) == 0) { red[row_l][wn * 2] = s; red[row_l][wn * 2 + 1] = q; }
    }
  }
  __syncthreads();
  #pragma unroll
  for (int m = 0; m < 2; m++) {
    #pragma unroll
    for (int r = 0; r < 4; r++) {
      int row_l = wm * 32 + m * 16 + (lane >> 4) * 4 + r;
      float4 rr = *(const float4*)&red[row_l][0];
      float mu = (rr.x + rr.z) * (1.f / HD);
      float var = (rr.y + rr.w) * (1.f / HD) - mu * mu;
      float inv = rsqrtf(var + 1e-5f);
      size_t rb = (size_t)(row0 + row_l) * HD;
      #pragma unroll
      for (int n = 0; n < 8; n++) {
        float v = (acc[m][n][r] - mu) * inv * gm[n] + bt[n];
        outF[rb + colb + n * 16] = v;
        if (OUTBF) outB[rb + colb + n * 16] = f2bf(v);
      }
    }
  }
}

// ---------- fused masked attention, MFMA 32x32x16, swapped operands ----------
__global__ __launch_bounds__(256) void k_attn(const ushort_t* __restrict__ qkb,
    const u32* __restrict__ adj, const int* __restrict__ offs,
    ushort_t* __restrict__ attOb) {
  int bid = blockIdx.x;               // b(4b) | h(3b) | qtr(2b)
  int qtr = bid & 3, hh = (bid >> 2) & 7, b = bid >> 5;
  int nstart = offs[b], len = offs[b + 1] - nstart;
  int q0blk = qtr * 128;
  if (q0blk >= len) return;

  __shared__ __align__(16) ushort_t K_lds[4 * 512 * 8];    // 32KB
  __shared__ __align__(16) ushort_t Kt_lds[64 * 32 * 8];   // 32KB
  __shared__ __align__(16) ushort_t P_lds[4 * 4 * 32 * 8]; // 8KB

  int tid = threadIdx.x;
  {
    const ushort_t* kg = qkb + (size_t)(b * S_MAX) * 512 + 256 + hh * 32;
    for (int t = tid; t < 512; t += 256) {
      const uint4* src = (const uint4*)(kg + (size_t)t * 512);
      uint4 v0 = src[0], v1 = src[1], v2 = src[2], v3 = src[3];
      *(uint4*)&K_lds[0 * 4096 + t * 8] = v0;
      *(uint4*)&K_lds[1 * 4096 + t * 8] = v1;
      *(uint4*)&K_lds[2 * 4096 + t * 8] = v2;
      *(uint4*)&K_lds[3 * 4096 + t * 8] = v3;
    }
  }
  __syncthreads();
  {
    int d = tid & 31, tg = tid >> 5;
    int cc = d >> 3, e = d & 7;
    for (int i = 0; i < 8; i++) {
      int t0 = tg * 64 + i * 8;
      u32 w0 = (u32)K_lds[cc * 4096 + (t0 + 0) * 8 + e] | ((u32)K_lds[cc * 4096 + (t0 + 1) * 8 + e] << 16);
      u32 w1 = (u32)K_lds[cc * 4096 + (t0 + 2) * 8 + e] | ((u32)K_lds[cc * 4096 + (t0 + 3) * 8 + e] << 16);
      u32 w2 = (u32)K_lds[cc * 4096 + (t0 + 4) * 8 + e] | ((u32)K_lds[cc * 4096 + (t0 + 5) * 8 + e] << 16);
      u32 w3 = (u32)K_lds[cc * 4096 + (t0 + 6) * 8 + e] | ((u32)K_lds[cc * 4096 + (t0 + 7) * 8 + e] << 16);
      uint4 pk = {w0, w1, w2, w3};
      *(uint4*)&Kt_lds[(t0 >> 3) * 256 + d * 8] = pk;
    }
  }
  __syncthreads();

  int w = tid >> 6, lane = tid & 63;
  int q0w = q0blk + w * 32;
  if (q0w >= len) return;   // no barriers below

  int lq = lane & 31, hf = lane >> 5;
  int q_abs = q0w + lq;
  const float SCALE = 0.17677669529663687f;  // 1/sqrt(32)

  size_t qrow = (size_t)(b * S_MAX + q_abs) * 512 + hh * 32;
  short8 qf0 = *(const short8*)(qkb + qrow + hf * 8);
  short8 qf1 = *(const short8*)(qkb + qrow + 16 + hf * 8);

  const uint4* ap = (const uint4*)(adj + (size_t)(b * S_MAX + q_abs) * ADJW);
  uint4 a0 = ap[0], a1 = ap[1], a2 = ap[2], a3 = ap[3];
  u32 aw[16] = {a0.x, a0.y, a0.z, a0.w, a1.x, a1.y, a1.z, a1.w,
                a2.x, a2.y, a2.z, a2.w, a3.x, a3.y, a3.z, a3.w};

  f32x16 oacc = {0.f,0.f,0.f,0.f,0.f,0.f,0.f,0.f,0.f,0.f,0.f,0.f,0.f,0.f,0.f,0.f};
  float lsum = 0.f;

  #pragma unroll
  for (int tt = 0; tt < 16; tt++) {
    int t0 = tt * 32;
    short8 ka0 = *(const short8*)&K_lds[hf * 4096 + (t0 + lq) * 8];
    short8 ka1 = *(const short8*)&K_lds[(2 + hf) * 4096 + (t0 + lq) * 8];
    f32x16 sc = {0.f,0.f,0.f,0.f,0.f,0.f,0.f,0.f,0.f,0.f,0.f,0.f,0.f,0.f,0.f,0.f};
    sc = __builtin_amdgcn_mfma_f32_32x32x16_bf16(ka0, qf0, sc, 0, 0, 0);
    sc = __builtin_amdgcn_mfma_f32_32x32x16_bf16(ka1, qf1, sc, 0, 0, 0);
    u32 word = aw[tt];
    float p[16];
    #pragma unroll
    for (int r = 0; r < 16; r++) {
      int tb = (r & 3) + 8 * (r >> 2) + 4 * hf;
      float pe = __expf(sc[r] * SCALE);
      p[r] = ((word >> tb) & 1u) ? 0.f : pe;
      lsum += p[r];
    }
    #pragma unroll
    for (int g = 0; g < 4; g++) {
      u32 lo = (u32)f2bf(p[4 * g]) | ((u32)f2bf(p[4 * g + 1]) << 16);
      u32 hi = (u32)f2bf(p[4 * g + 2]) | ((u32)f2bf(p[4 * g + 3]) << 16);
      uint2 pk = {lo, hi};
      *(uint2*)&P_lds[w * 1024 + g * 256 + lq * 8 + hf * 4] = pk;
    }
    short8 va0 = *(const short8*)&Kt_lds[(t0 / 8 + hf) * 256 + lq * 8];
    short8 va1 = *(const short8*)&Kt_lds[(t0 / 8 + 2 + hf) * 256 + lq * 8];
    short8 pb0 = *(const short8*)&P_lds[w * 1024 + hf * 256 + lq * 8];
    short8 pb1 = *(const short8*)&P_lds[w * 1024 + (2 + hf) * 256 + lq * 8];
    oacc = __builtin_amdgcn_mfma_f32_32x32x16_bf16(va0, pb0, oacc, 0, 0, 0);
    oacc = __builtin_amdgcn_mfma_f32_32x32x16_bf16(va1, pb1, oacc, 0, 0, 0);
  }

  float ltot = lsum + __shfl_xor(lsum, 32, 64);
  float inv = 1.f / ltot;
  if (q_abs < len) {
    int node = nstart + q_abs;
    ushort_t* op = attOb + (size_t)node * HD + hh * DH;
    #pragma unroll
    for (int g = 0; g < 4; g++) {
      float v0 = oacc[4 * g] * inv, v1 = oacc[4 * g + 1] * inv;
      float v2 = oacc[4 * g + 2] * inv, v3 = oacc[4 * g + 3] * inv;
      u32 lo = (u32)f2bf(v0) | ((u32)f2bf(v1) << 16);
      u32 hi = (u32)f2bf(v2) | ((u32)f2bf(v3) << 16);
      uint2 pk = {lo, hi};
      *(uint2*)(op + g * 8 + hf * 4) = pk;
    }
  }
}

extern "C" void kernel_launch(void* const* d_in, const int* in_sizes, int n_in,
                              void* d_out, int out_size, void* d_ws, size_t ws_size,
                              hipStream_t stream) {
  const float* h   = (const float*)d_in[0];
  const float* Wq  = (const float*)d_in[1];
  const float* bq  = (const float*)d_in[2];
  const float* Wk  = (const float*)d_in[3];
  const float* bk  = (const float*)d_in[4];
  // d_in[5], d_in[6] (Wv, bv) unused: reference V uses the K projection
  const float* Wo  = (const float*)d_in[7];
  const float* bo  = (const float*)d_in[8];
  const float* W1  = (const float*)d_in[9];
  const float* b1  = (const float*)d_in[10];
  const float* W2  = (const float*)d_in[11];
  const float* b2  = (const float*)d_in[12];
  const float* g1  = (const float*)d_in[13];
  const float* be1 = (const float*)d_in[14];
  const float* g2  = (const float*)d_in[15];
  const float* be2 = (const float*)d_in[16];
  const int* batch = (const int*)d_in[17];
  const int* ei    = (const int*)d_in[18];
  int N = in_sizes[0] / HD;       // 6400
  int E = in_sizes[18] / 2;       // 102400

  // workspace layout (~38 MB)
  char* ws = (char*)d_ws;
  ushort_t* xb    = (ushort_t*)(ws);                              // 4MB  [8192,256] bf16
  ushort_t* attOb = xb;                                           // alias (xb dead after QK gemm)
  ushort_t* qkb   = (ushort_t*)(ws + ((size_t)4 << 20));          // 8MB  [8192,512] bf16
  float*    h1    = (float*)(ws + ((size_t)12 << 20));            // 6.4MB fp32
  ushort_t* h1b   = (ushort_t*)(ws + ((size_t)19 << 20));         // 3.2MB
  ushort_t* ff1b  = (ushort_t*)(ws + ((size_t)23 << 20));         // 12.8MB
  char* wbase = ws + ((size_t)36 << 20);
  ushort_t* Wqkb = (ushort_t*)(wbase);                            // 256KB [512,256]
  ushort_t* Wob  = (ushort_t*)(wbase + (256 << 10));              // 128KB
  ushort_t* W1b  = (ushort_t*)(wbase + (384 << 10));              // 512KB [1024,256]
  ushort_t* W2b  = (ushort_t*)(wbase + (896 << 10));              // 512KB [256,1024]
  float*    bqk  = (float*)(wbase + (1408 << 10));                // 2KB  [512]
  u32*      adj  = (u32*)(wbase + (1536 << 10));                  // 512KB
  int*      offs = (int*)(ws + ((size_t)38 << 20));               // 128B

  hipMemsetAsync(adj, 0, (size_t)B_G * S_MAX * ADJW * 4, stream);
  k_offsets<<<1, 512, 0, stream>>>(batch, N, offs, bq, bk, bqk);
  k_mega<<<2800, 256, 0, stream>>>(h, offs, xb, ei, E, batch, adj,
                                   Wq, Wk, Wo, W1, W2,
                                   Wqkb, Wqkb + 65536, Wob, W1b, W2b);
  // fused Q|K projection: [8192,256] x [512,256]^T -> [8192,512] bf16
  k_mgemm<false, true><<<dim3(64, 4), 256, 0, stream>>>(xb, Wqkb, bqk, qkb, 512, HD);
  // attention -> compact [6400,256] bf16
  k_attn<<<B_G * NH * 4, 256, 0, stream>>>(qkb, adj, offs, attOb);
  // out-proj + residual(h) + LN1 -> h1 (fp32) + h1b (bf16)
  k_gemm_ln<true><<<N / 128, 512, 0, stream>>>(attOb, Wob, bo, h, g1, be1, h1, h1b, HD);
  // FFN up + relu
  k_mgemm<true, true><<<dim3(N / 128, 8), 256, 0, stream>>>(h1b, W1b, b1, ff1b, FFD, HD);
  // FFN down + residual(h1) + LN2 -> d_out (fp32)
  k_gemm_ln<false><<<N / 128, 512, 0, stream>>>(ff1b, W2b, b2, h1, g2, be2, (float*)d_out, nullptr, FFD);
}

// Round 5
// 103.492 us; speedup vs baseline: 3.6591x; 1.0418x over previous
//
#include <hip/hip_runtime.h>
#include <math.h>

typedef unsigned int u32;
typedef unsigned short ushort_t;
typedef __attribute__((ext_vector_type(8))) short short8;
typedef __attribute__((ext_vector_type(4))) float f32x4;
typedef __attribute__((ext_vector_type(16))) float f32x16;

#define B_G 16
#define S_MAX 512
#define NH 8
#define DH 32
#define HD 256
#define FFD 1024
#define ADJW 16            // u32 words per adjacency row (512 bits)

// ---------- bf16 helpers (RNE) ----------
__device__ __forceinline__ ushort_t f2bf(float f) {
  u32 u = __float_as_uint(f);
  u += 0x7fffu + ((u >> 16) & 1u);
  return (ushort_t)(u >> 16);
}

// async global->LDS, 16B per lane
__device__ __forceinline__ void gll16(const void* g, void* l) {
  __builtin_amdgcn_global_load_lds(
      (const __attribute__((address_space(1))) unsigned int*)g,
      (__attribute__((address_space(3))) unsigned int*)l, 16, 0, 0);
}

// ---------- prep: zero adj (512KB) + offsets + bias concat ----------
// 128 blocks x 256 thr; replaces hipMemsetAsync (rocclr fill node costs ~43us
// fixed inside a graph) and the old k_offsets kernel.
__global__ __launch_bounds__(256) void k_prep(u32* __restrict__ adj,
    const int* __restrict__ batch, int N, int* __restrict__ offs,
    const float* __restrict__ bq, const float* __restrict__ bk,
    float* __restrict__ bqk) {
  int tid = threadIdx.x, blk = blockIdx.x;
  uint4 z = {0u, 0u, 0u, 0u};
  ((uint4*)adj)[blk * 256 + tid] = z;
  if (blk == 0) {
    bqk[tid] = bq[tid];
    bqk[HD + tid] = bk[tid];
    if (tid <= B_G) {
      if (tid == B_G) { offs[B_G] = N; }
      else {
        int lo = 0, hi = N;
        while (lo < hi) { int mid = (lo + hi) >> 1; if (batch[mid] < tid) lo = mid + 1; else hi = mid; }
        offs[tid] = lo;
      }
    }
  }
}

// ---------- mega prep: dense-scatter+zero | adjacency | weight cvt ----------
// blocks 0..2047: 4 dense rows each (scatter h or zero pad)
// blocks 2048..2447: edges -> adj atomicOr (adj zeroed by k_prep)
// blocks 2448..2799: fp32->bf16 weight convert (5 segments)
__global__ __launch_bounds__(256) void k_mega(
    const float* __restrict__ h, const int* __restrict__ offs, ushort_t* __restrict__ xb,
    const int* __restrict__ ei, int E, const int* __restrict__ batch, u32* __restrict__ adj,
    const float* __restrict__ wa, const float* __restrict__ wb, const float* __restrict__ wc,
    const float* __restrict__ wd, const float* __restrict__ we,
    ushort_t* __restrict__ oa, ushort_t* __restrict__ ob, ushort_t* __restrict__ oc,
    ushort_t* __restrict__ od, ushort_t* __restrict__ oe) {
  int blk = blockIdx.x, tid = threadIdx.x;
  if (blk < 2048) {
    int row = blk * 4 + (tid >> 6);
    int c = tid & 63;
    int b = row >> 9, pos = row & 511;
    int len = offs[b + 1] - offs[b];
    uint2 pk = {0u, 0u};
    if (pos < len) {
      int node = offs[b] + pos;
      float4 v = ((const float4*)(h + (size_t)node * HD))[c];
      pk.x = (u32)f2bf(v.x) | ((u32)f2bf(v.y) << 16);
      pk.y = (u32)f2bf(v.z) | ((u32)f2bf(v.w) << 16);
    }
    *(uint2*)(xb + (size_t)row * HD + c * 4) = pk;
  } else if (blk < 2448) {
    int e = (blk - 2048) * 256 + tid;
    if (e >= E) return;
    int s = ei[e], d = ei[E + e];
    int b = batch[s];
    int o = offs[b];
    atomicOr(&adj[(b * S_MAX + (s - o)) * ADJW + ((d - o) >> 5)], 1u << ((d - o) & 31));
  } else {
    int bb = blk - 2448;
    const float* src; ushort_t* dst; int off;
    if (bb < 32)       { src = wa; dst = oa; off = bb; }
    else if (bb < 64)  { src = wb; dst = ob; off = bb - 32; }
    else if (bb < 96)  { src = wc; dst = oc; off = bb - 64; }
    else if (bb < 224) { src = wd; dst = od; off = bb - 96; }
    else               { src = we; dst = oe; off = bb - 224; }
    size_t i = (size_t)off * 2048 + tid * 8;
    float4 v0 = *(const float4*)&src[i];
    float4 v1 = *(const float4*)&src[i + 4];
    uint4 pk;
    pk.x = (u32)f2bf(v0.x) | ((u32)f2bf(v0.y) << 16);
    pk.y = (u32)f2bf(v0.z) | ((u32)f2bf(v0.w) << 16);
    pk.z = (u32)f2bf(v1.x) | ((u32)f2bf(v1.y) << 16);
    pk.w = (u32)f2bf(v1.z) | ((u32)f2bf(v1.w) << 16);
    *(uint4*)&dst[i] = pk;
  }
}

// ---------- MFMA bf16 GEMM, 128x128 tile, BK=64 ----------
// LDS element (r,k) at r*64 + ((k/8)^(r&7))*8 + k%8 via pre-swizzled global src.
template<bool RELU, bool OUTBF>
__global__ __launch_bounds__(256) void k_mgemm(const ushort_t* __restrict__ A,
    const ushort_t* __restrict__ W, const float* __restrict__ bias,
    void* __restrict__ Cout, int Ncols, int Kdim) {
  __shared__ __align__(16) ushort_t As[128 * 64];
  __shared__ __align__(16) ushort_t Bs[128 * 64];
  int tid = threadIdx.x;
  int wid = tid >> 6, lane = tid & 63;
  int wm = wid >> 1, wn = wid & 1;
  int arow0 = blockIdx.x * 128, bcol0 = blockIdx.y * 128;

  const ushort_t* gA[4]; const ushort_t* gB[4];
  ushort_t* lA[4]; ushort_t* lB[4];
  #pragma unroll
  for (int i = 0; i < 4; i++) {
    int s = i * 256 + tid;
    int r = s >> 3, c = (s & 7) ^ (r & 7);
    gA[i] = A + (size_t)(arow0 + r) * Kdim + c * 8;
    gB[i] = W + (size_t)(bcol0 + r) * Kdim + c * 8;
    lA[i] = &As[(i * 256 + wid * 64) * 8];
    lB[i] = &Bs[(i * 256 + wid * 64) * 8];
  }

  f32x4 acc[4][4];
  #pragma unroll
  for (int i = 0; i < 4; i++)
    #pragma unroll
    for (int j = 0; j < 4; j++) { f32x4 z = {0.f, 0.f, 0.f, 0.f}; acc[i][j] = z; }

  for (int k0 = 0; k0 < Kdim; k0 += 64) {
    __syncthreads();
    #pragma unroll
    for (int i = 0; i < 4; i++) { gll16(gA[i] + k0, lA[i]); gll16(gB[i] + k0, lB[i]); }
    asm volatile("s_waitcnt vmcnt(0)" ::: "memory");
    __syncthreads();
    #pragma unroll
    for (int ks = 0; ks < 2; ks++) {
      short8 af[4], bf[4];
      #pragma unroll
      for (int i = 0; i < 4; i++) {
        int row = wm * 64 + i * 16 + (lane & 15);
        int ck = (ks * 4 + (lane >> 4)) ^ (row & 7);
        af[i] = *(const short8*)&As[row * 64 + ck * 8];
      }
      #pragma unroll
      for (int j = 0; j < 4; j++) {
        int row = wn * 64 + j * 16 + (lane & 15);
        int ck = (ks * 4 + (lane >> 4)) ^ (row & 7);
        bf[j] = *(const short8*)&Bs[row * 64 + ck * 8];
      }
      #pragma unroll
      for (int i = 0; i < 4; i++)
        #pragma unroll
        for (int j = 0; j < 4; j++)
          acc[i][j] = __builtin_amdgcn_mfma_f32_16x16x32_bf16(af[i], bf[j], acc[i][j], 0, 0, 0);
    }
  }

  float bj[4];
  #pragma unroll
  for (int j = 0; j < 4; j++)
    bj[j] = bias[bcol0 + wn * 64 + j * 16 + (lane & 15)];
  #pragma unroll
  for (int i = 0; i < 4; i++) {
    #pragma unroll
    for (int r = 0; r < 4; r++) {
      int row = arow0 + wm * 64 + i * 16 + (lane >> 4) * 4 + r;
      size_t base = (size_t)row * Ncols + bcol0 + wn * 64 + (lane & 15);
      #pragma unroll
      for (int j = 0; j < 4; j++) {
        float v = acc[i][j][r] + bj[j];
        if (RELU) v = fmaxf(v, 0.f);
        if (OUTBF) ((ushort_t*)Cout)[base + j * 16] = f2bf(v);
        else       ((float*)Cout)[base + j * 16] = v;
      }
    }
  }
}

// ---------- MFMA GEMM (M-tile 128 x all-256 cols) + residual + LayerNorm ----------
// 512 threads = 8 waves: wm=wid>>1 (32 rows), wn=wid&1 (128 cols). BK=64.
// out = LN(A*W^T + bias + R) * gamma + beta; fp32 out + optional bf16 copy.
template<bool OUTBF>
__global__ __launch_bounds__(512) void k_gemm_ln(const ushort_t* __restrict__ A,
    const ushort_t* __restrict__ W, const float* __restrict__ bias,
    const float* __restrict__ R, const float* __restrict__ gamma,
    const float* __restrict__ beta, float* __restrict__ outF,
    ushort_t* __restrict__ outB, int Kdim) {
  __shared__ __align__(16) ushort_t As[128 * 64];   // 16KB
  __shared__ __align__(16) ushort_t Bs[256 * 64];   // 32KB
  __shared__ float red[128][4];                     // [row][wn*2 + {sum,sq}]
  int tid = threadIdx.x;
  int wid = tid >> 6, lane = tid & 63;
  int wm = wid >> 1, wn = wid & 1;
  int row0 = blockIdx.x * 128;

  const ushort_t* gA[2]; ushort_t* lA[2];
  const ushort_t* gB[4]; ushort_t* lB[4];
  #pragma unroll
  for (int i = 0; i < 2; i++) {
    int s = i * 512 + tid;
    int r = s >> 3, c = (s & 7) ^ (r & 7);
    gA[i] = A + (size_t)(row0 + r) * Kdim + c * 8;
    lA[i] = &As[(i * 512 + wid * 64) * 8];
  }
  #pragma unroll
  for (int i = 0; i < 4; i++) {
    int s = i * 512 + tid;
    int r = s >> 3, c = (s & 7) ^ (r & 7);
    gB[i] = W + (size_t)r * Kdim + c * 8;
    lB[i] = &Bs[(i * 512 + wid * 64) * 8];
  }

  f32x4 acc[2][8];
  #pragma unroll
  for (int m = 0; m < 2; m++)
    #pragma unroll
    for (int n = 0; n < 8; n++) { f32x4 z = {0.f, 0.f, 0.f, 0.f}; acc[m][n] = z; }

  for (int k0 = 0; k0 < Kdim; k0 += 64) {
    __syncthreads();
    #pragma unroll
    for (int i = 0; i < 2; i++) gll16(gA[i] + k0, lA[i]);
    #pragma unroll
    for (int i = 0; i < 4; i++) gll16(gB[i] + k0, lB[i]);
    asm volatile("s_waitcnt vmcnt(0)" ::: "memory");
    __syncthreads();
    #pragma unroll
    for (int ks = 0; ks < 2; ks++) {
      short8 af[2], bf[8];
      #pragma unroll
      for (int m = 0; m < 2; m++) {
        int row = wm * 32 + m * 16 + (lane & 15);
        int ck = (ks * 4 + (lane >> 4)) ^ (row & 7);
        af[m] = *(const short8*)&As[row * 64 + ck * 8];
      }
      #pragma unroll
      for (int n = 0; n < 8; n++) {
        int row = wn * 128 + n * 16 + (lane & 15);
        int ck = (ks * 4 + (lane >> 4)) ^ (row & 7);
        bf[n] = *(const short8*)&Bs[row * 64 + ck * 8];
      }
      #pragma unroll
      for (int m = 0; m < 2; m++)
        #pragma unroll
        for (int n = 0; n < 8; n++)
          acc[m][n] = __builtin_amdgcn_mfma_f32_16x16x32_bf16(af[m], bf[n], acc[m][n], 0, 0, 0);
    }
  }

  int colb = wn * 128 + (lane & 15);
  float bc[8], gm[8], bt[8];
  #pragma unroll
  for (int n = 0; n < 8; n++) {
    bc[n] = bias[colb + n * 16];
    gm[n] = gamma[colb + n * 16];
    bt[n] = beta[colb + n * 16];
  }
  // v = acc + bias + residual; per-row partial sums over this wave's 128 cols
  #pragma unroll
  for (int m = 0; m < 2; m++) {
    #pragma unroll
    for (int r = 0; r < 4; r++) {
      int row_l = wm * 32 + m * 16 + (lane >> 4) * 4 + r;
      const float* Rrow = R + (size_t)(row0 + row_l) * HD;
      float s = 0.f, q = 0.f;
      #pragma unroll
      for (int n = 0; n < 8; n++) {
        float v = acc[m][n][r] + bc[n] + Rrow[colb + n * 16];
        acc[m][n][r] = v;
        s += v; q += v * v;
      }
      #pragma unroll
      for (int o = 1; o < 16; o <<= 1) { s += __shfl_xor(s, o, 64); q += __shfl_xor(q, o, 64); }
      if ((lane & 15) == 0) { red[row_l][wn * 2] = s; red[row_l][wn * 2 + 1] = q; }
    }
  }
  __syncthreads();
  #pragma unroll
  for (int m = 0; m < 2; m++) {
    #pragma unroll
    for (int r = 0; r < 4; r++) {
      int row_l = wm * 32 + m * 16 + (lane >> 4) * 4 + r;
      float4 rr = *(const float4*)&red[row_l][0];
      float mu = (rr.x + rr.z) * (1.f / HD);
      float var = (rr.y + rr.w) * (1.f / HD) - mu * mu;
      float inv = rsqrtf(var + 1e-5f);
      size_t rb = (size_t)(row0 + row_l) * HD;
      #pragma unroll
      for (int n = 0; n < 8; n++) {
        float v = (acc[m][n][r] - mu) * inv * gm[n] + bt[n];
        outF[rb + colb + n * 16] = v;
        if (OUTBF) outB[rb + colb + n * 16] = f2bf(v);
      }
    }
  }
}

// ---------- fused masked attention, MFMA 32x32x16, swapped operands ----------
__global__ __launch_bounds__(256) void k_attn(const ushort_t* __restrict__ qkb,
    const u32* __restrict__ adj, const int* __restrict__ offs,
    ushort_t* __restrict__ attOb) {
  int bid = blockIdx.x;               // b(4b) | h(3b) | qtr(2b)
  int qtr = bid & 3, hh = (bid >> 2) & 7, b = bid >> 5;
  int nstart = offs[b], len = offs[b + 1] - nstart;
  int q0blk = qtr * 128;
  if (q0blk >= len) return;

  __shared__ __align__(16) ushort_t K_lds[4 * 512 * 8];    // 32KB
  __shared__ __align__(16) ushort_t Kt_lds[64 * 32 * 8];   // 32KB
  __shared__ __align__(16) ushort_t P_lds[4 * 4 * 32 * 8]; // 8KB

  int tid = threadIdx.x;
  {
    const ushort_t* kg = qkb + (size_t)(b * S_MAX) * 512 + 256 + hh * 32;
    for (int t = tid; t < 512; t += 256) {
      const uint4* src = (const uint4*)(kg + (size_t)t * 512);
      uint4 v0 = src[0], v1 = src[1], v2 = src[2], v3 = src[3];
      *(uint4*)&K_lds[0 * 4096 + t * 8] = v0;
      *(uint4*)&K_lds[1 * 4096 + t * 8] = v1;
      *(uint4*)&K_lds[2 * 4096 + t * 8] = v2;
      *(uint4*)&K_lds[3 * 4096 + t * 8] = v3;
    }
  }
  __syncthreads();
  {
    int d = tid & 31, tg = tid >> 5;
    int cc = d >> 3, e = d & 7;
    for (int i = 0; i < 8; i++) {
      int t0 = tg * 64 + i * 8;
      u32 w0 = (u32)K_lds[cc * 4096 + (t0 + 0) * 8 + e] | ((u32)K_lds[cc * 4096 + (t0 + 1) * 8 + e] << 16);
      u32 w1 = (u32)K_lds[cc * 4096 + (t0 + 2) * 8 + e] | ((u32)K_lds[cc * 4096 + (t0 + 3) * 8 + e] << 16);
      u32 w2 = (u32)K_lds[cc * 4096 + (t0 + 4) * 8 + e] | ((u32)K_lds[cc * 4096 + (t0 + 5) * 8 + e] << 16);
      u32 w3 = (u32)K_lds[cc * 4096 + (t0 + 6) * 8 + e] | ((u32)K_lds[cc * 4096 + (t0 + 7) * 8 + e] << 16);
      uint4 pk = {w0, w1, w2, w3};
      *(uint4*)&Kt_lds[(t0 >> 3) * 256 + d * 8] = pk;
    }
  }
  __syncthreads();

  int w = tid >> 6, lane = tid & 63;
  int q0w = q0blk + w * 32;
  if (q0w >= len) return;   // no barriers below

  int lq = lane & 31, hf = lane >> 5;
  int q_abs = q0w + lq;
  const float SCALE = 0.17677669529663687f;  // 1/sqrt(32)

  size_t qrow = (size_t)(b * S_MAX + q_abs) * 512 + hh * 32;
  short8 qf0 = *(const short8*)(qkb + qrow + hf * 8);
  short8 qf1 = *(const short8*)(qkb + qrow + 16 + hf * 8);

  const uint4* ap = (const uint4*)(adj + (size_t)(b * S_MAX + q_abs) * ADJW);
  uint4 a0 = ap[0], a1 = ap[1], a2 = ap[2], a3 = ap[3];
  u32 aw[16] = {a0.x, a0.y, a0.z, a0.w, a1.x, a1.y, a1.z, a1.w,
                a2.x, a2.y, a2.z, a2.w, a3.x, a3.y, a3.z, a3.w};

  f32x16 oacc = {0.f,0.f,0.f,0.f,0.f,0.f,0.f,0.f,0.f,0.f,0.f,0.f,0.f,0.f,0.f,0.f};
  float lsum = 0.f;

  #pragma unroll
  for (int tt = 0; tt < 16; tt++) {
    int t0 = tt * 32;
    short8 ka0 = *(const short8*)&K_lds[hf * 4096 + (t0 + lq) * 8];
    short8 ka1 = *(const short8*)&K_lds[(2 + hf) * 4096 + (t0 + lq) * 8];
    f32x16 sc = {0.f,0.f,0.f,0.f,0.f,0.f,0.f,0.f,0.f,0.f,0.f,0.f,0.f,0.f,0.f,0.f};
    sc = __builtin_amdgcn_mfma_f32_32x32x16_bf16(ka0, qf0, sc, 0, 0, 0);
    sc = __builtin_amdgcn_mfma_f32_32x32x16_bf16(ka1, qf1, sc, 0, 0, 0);
    u32 word = aw[tt];
    float p[16];
    #pragma unroll
    for (int r = 0; r < 16; r++) {
      int tb = (r & 3) + 8 * (r >> 2) + 4 * hf;
      float pe = __expf(sc[r] * SCALE);
      p[r] = ((word >> tb) & 1u) ? 0.f : pe;
      lsum += p[r];
    }
    #pragma unroll
    for (int g = 0; g < 4; g++) {
      u32 lo = (u32)f2bf(p[4 * g]) | ((u32)f2bf(p[4 * g + 1]) << 16);
      u32 hi = (u32)f2bf(p[4 * g + 2]) | ((u32)f2bf(p[4 * g + 3]) << 16);
      uint2 pk = {lo, hi};
      *(uint2*)&P_lds[w * 1024 + g * 256 + lq * 8 + hf * 4] = pk;
    }
    short8 va0 = *(const short8*)&Kt_lds[(t0 / 8 + hf) * 256 + lq * 8];
    short8 va1 = *(const short8*)&Kt_lds[(t0 / 8 + 2 + hf) * 256 + lq * 8];
    short8 pb0 = *(const short8*)&P_lds[w * 1024 + hf * 256 + lq * 8];
    short8 pb1 = *(const short8*)&P_lds[w * 1024 + (2 + hf) * 256 + lq * 8];
    oacc = __builtin_amdgcn_mfma_f32_32x32x16_bf16(va0, pb0, oacc, 0, 0, 0);
    oacc = __builtin_amdgcn_mfma_f32_32x32x16_bf16(va1, pb1, oacc, 0, 0, 0);
  }

  float ltot = lsum + __shfl_xor(lsum, 32, 64);
  float inv = 1.f / ltot;
  if (q_abs < len) {
    int node = nstart + q_abs;
    ushort_t* op = attOb + (size_t)node * HD + hh * DH;
    #pragma unroll
    for (int g = 0; g < 4; g++) {
      float v0 = oacc[4 * g] * inv, v1 = oacc[4 * g + 1] * inv;
      float v2 = oacc[4 * g + 2] * inv, v3 = oacc[4 * g + 3] * inv;
      u32 lo = (u32)f2bf(v0) | ((u32)f2bf(v1) << 16);
      u32 hi = (u32)f2bf(v2) | ((u32)f2bf(v3) << 16);
      uint2 pk = {lo, hi};
      *(uint2*)(op + g * 8 + hf * 4) = pk;
    }
  }
}

extern "C" void kernel_launch(void* const* d_in, const int* in_sizes, int n_in,
                              void* d_out, int out_size, void* d_ws, size_t ws_size,
                              hipStream_t stream) {
  const float* h   = (const float*)d_in[0];
  const float* Wq  = (const float*)d_in[1];
  const float* bq  = (const float*)d_in[2];
  const float* Wk  = (const float*)d_in[3];
  const float* bk  = (const float*)d_in[4];
  // d_in[5], d_in[6] (Wv, bv) unused: reference V uses the K projection
  const float* Wo  = (const float*)d_in[7];
  const float* bo  = (const float*)d_in[8];
  const float* W1  = (const float*)d_in[9];
  const float* b1  = (const float*)d_in[10];
  const float* W2  = (const float*)d_in[11];
  const float* b2  = (const float*)d_in[12];
  const float* g1  = (const float*)d_in[13];
  const float* be1 = (const float*)d_in[14];
  const float* g2  = (const float*)d_in[15];
  const float* be2 = (const float*)d_in[16];
  const int* batch = (const int*)d_in[17];
  const int* ei    = (const int*)d_in[18];
  int N = in_sizes[0] / HD;       // 6400
  int E = in_sizes[18] / 2;       // 102400

  // workspace layout (~38 MB)
  char* ws = (char*)d_ws;
  ushort_t* xb    = (ushort_t*)(ws);                              // 4MB  [8192,256] bf16
  ushort_t* attOb = xb;                                           // alias (xb dead after QK gemm)
  ushort_t* qkb   = (ushort_t*)(ws + ((size_t)4 << 20));          // 8MB  [8192,512] bf16
  float*    h1    = (float*)(ws + ((size_t)12 << 20));            // 6.4MB fp32
  ushort_t* h1b   = (ushort_t*)(ws + ((size_t)19 << 20));         // 3.2MB
  ushort_t* ff1b  = (ushort_t*)(ws + ((size_t)23 << 20));         // 12.8MB
  char* wbase = ws + ((size_t)36 << 20);
  ushort_t* Wqkb = (ushort_t*)(wbase);                            // 256KB [512,256]
  ushort_t* Wob  = (ushort_t*)(wbase + (256 << 10));              // 128KB
  ushort_t* W1b  = (ushort_t*)(wbase + (384 << 10));              // 512KB [1024,256]
  ushort_t* W2b  = (ushort_t*)(wbase + (896 << 10));              // 512KB [256,1024]
  float*    bqk  = (float*)(wbase + (1408 << 10));                // 2KB  [512]
  u32*      adj  = (u32*)(wbase + (1536 << 10));                  // 512KB
  int*      offs = (int*)(ws + ((size_t)38 << 20));               // 128B

  // zero adj + offsets + bias concat (replaces hipMemsetAsync: in-graph
  // rocclr fill node measured ~43us fixed cost regardless of size)
  k_prep<<<128, 256, 0, stream>>>(adj, batch, N, offs, bq, bk, bqk);
  k_mega<<<2800, 256, 0, stream>>>(h, offs, xb, ei, E, batch, adj,
                                   Wq, Wk, Wo, W1, W2,
                                   Wqkb, Wqkb + 65536, Wob, W1b, W2b);
  // fused Q|K projection: [8192,256] x [512,256]^T -> [8192,512] bf16
  k_mgemm<false, true><<<dim3(64, 4), 256, 0, stream>>>(xb, Wqkb, bqk, qkb, 512, HD);
  // attention -> compact [6400,256] bf16
  k_attn<<<B_G * NH * 4, 256, 0, stream>>>(qkb, adj, offs, attOb);
  // out-proj + residual(h) + LN1 -> h1 (fp32) + h1b (bf16)
  k_gemm_ln<true><<<N / 128, 512, 0, stream>>>(attOb, Wob, bo, h, g1, be1, h1, h1b, HD);
  // FFN up + relu
  k_mgemm<true, true><<<dim3(N / 128, 8), 256, 0, stream>>>(h1b, W1b, b1, ff1b, FFD, HD);
  // FFN down + residual(h1) + LN2 -> d_out (fp32)
  k_gemm_ln<false><<<N / 128, 512, 0, stream>>>(ff1b, W2b, b2, h1, g2, be2, (float*)d_out, nullptr, FFD);
}